// Round 3
// baseline (152.288 us; speedup 1.0000x reference)
//
#include <hip/hip_runtime.h>
#include <hip/hip_bf16.h>
#include <math.h>

#define B_SZ 512
#define D_SZ 2048
#define M_SZ 128
#define H_SZ 128
#define BCHUNK 64
#define NCHUNKS (B_SZ / BCHUNK)

typedef __attribute__((ext_vector_type(8))) short bf16x8;
typedef __attribute__((ext_vector_type(4))) float f32x4;
typedef __attribute__((ext_vector_type(4))) unsigned short us4;

__device__ __forceinline__ unsigned short f2bf(float f) {
    unsigned u = __builtin_bit_cast(unsigned, f);
    u += 0x7fffu + ((u >> 16) & 1u);   // round-to-nearest-even
    return (unsigned short)(u >> 16);
}

// tanh-form gelu: h * sigmoid(1.59577 h + 0.0713548 h^3).
// |err vs exact erf-gelu| <= ~3.5e-4 (peak near |h|~2); our |h| <~ 1.4.
__device__ __forceinline__ float gelu_fast(float h) {
    float u = h * h;
    float z = h * fmaf(0.0713548162726f, u, 1.5957691216057308f);
    float e = __expf(-z);
    return __fdividef(h, 1.0f + e);
}

__global__ __launch_bounds__(256, 3) void nlm_kernel(
    const float* __restrict__ x,   // [B, D, M]
    const float* __restrict__ W1,  // [D, H, M]
    const float* __restrict__ b1,  // [D, H]
    const float* __restrict__ W2,  // [D, H]
    const float* __restrict__ b2,  // [D]
    float* __restrict__ out)       // [B, D]
{
    // LDS rows = 128 bf16 = 256 B, XOR-swizzled (byte ^= (row&7)<<4) for
    // conflict-free ds_read_b128 fragment reads (G4 / T2).
    __shared__ __align__(16) unsigned short W1s[H_SZ * M_SZ];   // 32 KB
    __shared__ __align__(16) unsigned short Xs[BCHUNK * M_SZ];  // 16 KB

    const int bid = blockIdx.x;
    // XCD-aware swizzle: XCD k owns d in [k*256,(k+1)*256).
    const int d = (bid & 7) * 256 + (bid >> 3);

    const int tid  = threadIdx.x;
    const int l    = tid & 63;
    const int w    = tid >> 6;     // wave id: owns B-rows [w*16, w*16+16), ALL 128 H
    const int lrow = l & 15;
    const int lk   = l >> 4;
    const int swz  = (lrow & 7) << 4;

    // ---- stage W1[d] -> LDS bf16 (64 KB contiguous, fully coalesced) ----
    const float* W1d = W1 + (size_t)d * (H_SZ * M_SZ);
    #pragma unroll
    for (int i = 0; i < 16; ++i) {
        int idx = tid + i * 256;          // float4 index 0..4095
        int r = idx >> 5, c4 = idx & 31;
        const float4 v = *(const float4*)(W1d + (r << 7) + (c4 << 2));
        us4 u; u.x = f2bf(v.x); u.y = f2bf(v.y); u.z = f2bf(v.z); u.w = f2bf(v.w);
        int byte = (r << 8) + ((c4 << 3) ^ ((r & 7) << 4));
        *(us4*)((char*)W1s + byte) = u;
    }

    // ---- per-lane W2/b1 (H index = n*16 + lrow), broadcast loads, L1-cached ----
    float w2r[8], b1r[8];
    #pragma unroll
    for (int n = 0; n < 8; ++n) {
        w2r[n] = W2[(size_t)d * H_SZ + n * 16 + lrow];
        b1r[n] = b1[(size_t)d * H_SZ + n * 16 + lrow];
    }
    const float b2v = b2[d];

    // ---- issue chunk-0 X loads into registers (T14 issue-early) ----
    const int xr_row = tid >> 5;          // base row within chunk (0..7)
    const int xr_c4  = tid & 31;          // float4 column
    float4 xr[8];
    #pragma unroll
    for (int i = 0; i < 8; ++i)
        xr[i] = *(const float4*)(x + ((size_t)(xr_row + i * 8) * D_SZ + d) * M_SZ + (xr_c4 << 2));

    for (int c = 0; c < NCHUNKS; ++c) {
        // ---- consume staged regs: convert + write Xs ----
        #pragma unroll
        for (int i = 0; i < 8; ++i) {
            int r = xr_row + i * 8;
            us4 u; u.x = f2bf(xr[i].x); u.y = f2bf(xr[i].y);
                   u.z = f2bf(xr[i].z); u.w = f2bf(xr[i].w);
            int byte = (r << 8) + ((xr_c4 << 3) ^ ((r & 7) << 4));
            *(us4*)((char*)Xs + byte) = u;
        }
        __syncthreads();   // bar1: Xs (and W1s/regs on c==0) ready; nothing in flight

        // ---- issue next chunk's X loads; in flight across MFMA + epilogue ----
        if (c + 1 < NCHUNKS) {
            const size_t b0n = (size_t)(c + 1) * BCHUNK;
            #pragma unroll
            for (int i = 0; i < 8; ++i)
                xr[i] = *(const float4*)(x + ((b0n + xr_row + i * 8) * D_SZ + d) * M_SZ + (xr_c4 << 2));
        }

        // ---- MFMA: this wave's 16 rows x all 128 H, K = M = 128 ----
        f32x4 acc[8];
        #pragma unroll
        for (int n = 0; n < 8; ++n)
            acc[n] = (f32x4){0.f, 0.f, 0.f, 0.f};

        #pragma unroll
        for (int k = 0; k < 4; ++k) {
            const int colb = (k << 6) + (lk << 4);   // byte offset of 8 bf16
            const int arow = w * 16 + lrow;          // B row
            bf16x8 a = *(const bf16x8*)((const char*)Xs + (arow << 8) + (colb ^ swz));
            bf16x8 bb[8];
            #pragma unroll
            for (int n = 0; n < 8; ++n) {
                int row = n * 16 + lrow;             // H row of W1
                bb[n] = *(const bf16x8*)((const char*)W1s + (row << 8) + (colb ^ swz));
            }
            #pragma unroll
            for (int n = 0; n < 8; ++n)
                acc[n] = __builtin_amdgcn_mfma_f32_16x16x32_bf16(a, bb[n], acc[n], 0, 0, 0);
        }

        // ---- bar2: raw s_barrier, NO vmcnt drain (prefetch stays in flight).
        // All ds_reads above are retired (MFMA data deps force lgkmcnt waits).
        asm volatile("" ::: "memory");
        __builtin_amdgcn_sched_barrier(0);
        __builtin_amdgcn_s_barrier();
        __builtin_amdgcn_sched_barrier(0);
        asm volatile("" ::: "memory");

        // ---- epilogue: +b1, fast gelu, dot W2, intra-wave reduce over H ----
        // C/D layout: col(H) = n*16 + (lane&15), row(B) = w*16 + (lane>>4)*4 + reg  [m89]
        float p[4] = {0.f, 0.f, 0.f, 0.f};
        #pragma unroll
        for (int n = 0; n < 8; ++n) {
            const float w2v = w2r[n];
            const float b1v = b1r[n];
            #pragma unroll
            for (int r = 0; r < 4; ++r) {
                float h = acc[n][r] + b1v;
                p[r] += gelu_fast(h) * w2v;
            }
        }

        // reduce over the 16 lanes sharing the same (lk, reg) -> sums all 128 H
        #pragma unroll
        for (int off = 1; off < 16; off <<= 1)
            #pragma unroll
            for (int r = 0; r < 4; ++r)
                p[r] += __shfl_xor(p[r], off, 64);

        if (lrow == 0) {
            #pragma unroll
            for (int r = 0; r < 4; ++r)
                out[(size_t)(c * BCHUNK + w * 16 + lk * 4 + r) * D_SZ + d] = p[r] + b2v;
        }
    }
}

extern "C" void kernel_launch(void* const* d_in, const int* in_sizes, int n_in,
                              void* d_out, int out_size, void* d_ws, size_t ws_size,
                              hipStream_t stream) {
    const float* x  = (const float*)d_in[0];
    const float* W1 = (const float*)d_in[1];
    const float* b1 = (const float*)d_in[2];
    const float* W2 = (const float*)d_in[3];
    const float* b2 = (const float*)d_in[4];
    float* out = (float*)d_out;

    hipLaunchKernelGGL(nlm_kernel, dim3(D_SZ), dim3(256), 0, stream,
                       x, W1, b1, W2, b2, out);
}